// Round 1
// baseline (270.070 us; speedup 1.0000x reference)
//
#include <hip/hip_runtime.h>
#include <hip/hip_bf16.h>

#define HW 16384
#define W 128
#define C 128
#define HID 256

// ---------------- kernel 0: zero the stat accumulators ----------------
__global__ void zero_acc_kernel(float* acc) {
    acc[0] = 0.f;
    acc[1] = 0.f;
}

// ---------------- kernel 1: q/k/v 1x1 convs, write [pix][ch] ----------------
// grid 1024, block 256. 16 pixels per block.
__global__ void qkv_kernel(const float* __restrict__ q_in, const float* __restrict__ k_in,
                           const float* __restrict__ v_in,
                           const float* __restrict__ w_q, const float* __restrict__ w_k,
                           const float* __restrict__ w_v,
                           float* __restrict__ q_t, float* __restrict__ k_t,
                           float* __restrict__ v_t) {
    __shared__ float xs[3][C * 16];
    const int p0 = blockIdx.x * 16;
    const int t = threadIdx.x;

    #pragma unroll
    for (int it = 0; it < 8; ++it) {
        int e = t + 256 * it;          // e = c*16 + j
        int c = e >> 4, j = e & 15;
        xs[0][e] = q_in[c * HW + p0 + j];
        xs[1][e] = k_in[c * HW + p0 + j];
        xs[2][e] = v_in[c * HW + p0 + j];
    }
    __syncthreads();

    const int o = t & 127, half = t >> 7;
    const float* Ws[3] = {w_q, w_k, w_v};
    float* outs[3] = {q_t, k_t, v_t};

    #pragma unroll
    for (int m = 0; m < 3; ++m) {
        float acc[8] = {0.f, 0.f, 0.f, 0.f, 0.f, 0.f, 0.f, 0.f};
        const float* Wr = Ws[m] + o * C;
        const float* xb = &xs[m][half * 8];
        for (int c = 0; c < C; ++c) {
            float w = Wr[c];
            const float* xr = xb + c * 16;
            #pragma unroll
            for (int i = 0; i < 8; ++i) acc[i] += w * xr[i];
        }
        float* op = outs[m];
        #pragma unroll
        for (int i = 0; i < 8; ++i) op[(p0 + half * 8 + i) * C + o] = acc[i];
    }
}

// ---------------- kernel 2: deformable sampling + attention ----------------
// grid 16384, block 128 (one pixel per block, thread = channel)
__global__ void attn_kernel(const float* __restrict__ q_t, const float* __restrict__ k_t,
                            const float* __restrict__ v_t, const float* __restrict__ deform,
                            float* __restrict__ ao_t) {
    __shared__ int   s_off[25][4];
    __shared__ float s_w[25][4];

    // XCD-chunk + 8x8 pixel-tile swizzle for L2 locality of the gathers
    int bid = blockIdx.x;
    int wg = (bid & 7) * 2048 + (bid >> 3);
    int tile = wg >> 6, inner = wg & 63;
    int y = (tile >> 4) * 8 + (inner >> 3);
    int x = (tile & 15) * 8 + (inner & 7);
    const int pix = y * W + x;
    const int c = threadIdx.x;

    const float dx = deform[pix];
    const float dy = deform[HW + pix];

    if (c < 25) {
        int iy = c / 5, ix = c - iy * 5;
        float vx = (float)x + (float)(ix - 2) + dx;
        float vy = (float)y + (float)(iy - 2) + dy;
        float x0f = floorf(vx), y0f = floorf(vy);
        float fx = vx - x0f, fy = vy - y0f;
        float wx[2] = {1.f - fx, fx};
        float wy[2] = {1.f - fy, fy};
        #pragma unroll
        for (int cy = 0; cy < 2; ++cy) {
            #pragma unroll
            for (int cx = 0; cx < 2; ++cx) {
                float xf = x0f + (float)cx;
                float yf = y0f + (float)cy;
                bool valid = (xf >= 0.f) & (xf <= 127.f) & (yf >= 0.f) & (yf <= 127.f);
                int xi = min(max((int)xf, 0), 127);
                int yi = min(max((int)yf, 0), 127);
                s_off[c][cy * 2 + cx] = (yi * W + xi) * C;
                s_w[c][cy * 2 + cx] = valid ? wx[cx] * wy[cy] : 0.f;
            }
        }
    }
    __syncthreads();

    const float qc = q_t[pix * C + c] * 0.25f;   // scale = 1/sqrt(16)

    float s[25], vv[25];
    #pragma unroll
    for (int p = 0; p < 25; ++p) {
        int o0 = s_off[p][0], o1 = s_off[p][1], o2 = s_off[p][2], o3 = s_off[p][3];
        float w0 = s_w[p][0], w1 = s_w[p][1], w2 = s_w[p][2], w3 = s_w[p][3];
        float ks = w0 * k_t[o0 + c] + w1 * k_t[o1 + c] + w2 * k_t[o2 + c] + w3 * k_t[o3 + c];
        float vs = w0 * v_t[o0 + c] + w1 * v_t[o1 + c] + w2 * v_t[o2 + c] + w3 * v_t[o3 + c];
        float sp = qc * ks;
        sp += __shfl_xor(sp, 1);
        sp += __shfl_xor(sp, 2);
        sp += __shfl_xor(sp, 4);
        sp += __shfl_xor(sp, 8);
        s[p] = sp;
        vv[p] = vs;
    }

    float m = s[0];
    #pragma unroll
    for (int p = 1; p < 25; ++p) m = fmaxf(m, s[p]);
    float sum = 0.f;
    #pragma unroll
    for (int p = 0; p < 25; ++p) {
        float e = __expf(s[p] - m);
        s[p] = e;
        sum += e;
    }
    float inv = 1.f / sum;
    float oc = 0.f;
    #pragma unroll
    for (int p = 0; p < 25; ++p) oc += s[p] * vv[p];

    ao_t[pix * C + c] = oc * inv;
}

// ---------------- kernel 3: fc + MLP + residual + stats ----------------
// grid 1024, block 256. 16 pixels per block. out2 goes straight into d_out [C][HW].
__global__ void mlp_kernel(const float* __restrict__ ao_t, const float* __restrict__ w_fc,
                           const float* __restrict__ w1, const float* __restrict__ b1,
                           const float* __restrict__ w2, const float* __restrict__ b2,
                           float* __restrict__ out2, float* __restrict__ accum) {
    __shared__ float xs[16 * C];    // ao[j][c]
    __shared__ float ys[16 * C];    // out1[j][o]
    __shared__ float hs[16 * HID];  // hid[j][h]
    __shared__ float rs[8];

    const int p0 = blockIdx.x * 16;
    const int t = threadIdx.x;

    #pragma unroll
    for (int it = 0; it < 8; ++it) {
        int e = t + 256 * it;
        xs[e] = ao_t[p0 * C + e];
    }
    __syncthreads();

    const int o = t & 127, half = t >> 7;
    float out1r[8];
    {
        float acc[8] = {0.f, 0.f, 0.f, 0.f, 0.f, 0.f, 0.f, 0.f};
        const float* Wr = w_fc + o * C;
        for (int c = 0; c < C; ++c) {
            float w = Wr[c];
            #pragma unroll
            for (int i = 0; i < 8; ++i) acc[i] += w * xs[(half * 8 + i) * C + c];
        }
        #pragma unroll
        for (int i = 0; i < 8; ++i) {
            out1r[i] = acc[i];
            ys[(half * 8 + i) * C + o] = acc[i];
        }
    }
    __syncthreads();
    {
        // hid: one hidden channel per thread (t in [0,256))
        float acc[16] = {0.f};
        const float* Wr = w1 + t * C;
        for (int c = 0; c < C; ++c) {
            float w = Wr[c];
            #pragma unroll
            for (int j = 0; j < 16; ++j) acc[j] += w * ys[j * C + c];
        }
        float bb = b1[t];
        #pragma unroll
        for (int j = 0; j < 16; ++j) {
            float v = acc[j] + bb;
            hs[j * HID + t] = (v >= 0.f) ? v : 0.2f * v;
        }
    }
    __syncthreads();
    float lsum = 0.f, lsq = 0.f;
    {
        float acc[8] = {0.f, 0.f, 0.f, 0.f, 0.f, 0.f, 0.f, 0.f};
        const float* Wr = w2 + o * HID;
        for (int h = 0; h < HID; ++h) {
            float w = Wr[h];
            #pragma unroll
            for (int i = 0; i < 8; ++i) acc[i] += w * hs[(half * 8 + i) * HID + h];
        }
        float bb = b2[o];
        #pragma unroll
        for (int i = 0; i < 8; ++i) {
            float v = out1r[i] + acc[i] + bb;
            out2[o * HW + p0 + half * 8 + i] = v;
            lsum += v;
            lsq += v * v;
        }
    }
    // block reduction for layernorm stats
    #pragma unroll
    for (int m = 1; m < 64; m <<= 1) {
        lsum += __shfl_xor(lsum, m);
        lsq  += __shfl_xor(lsq, m);
    }
    int wv = t >> 6, ln = t & 63;
    if (ln == 0) { rs[wv] = lsum; rs[4 + wv] = lsq; }
    __syncthreads();
    if (t == 0) {
        atomicAdd(&accum[0], rs[0] + rs[1] + rs[2] + rs[3]);
        atomicAdd(&accum[1], rs[4] + rs[5] + rs[6] + rs[7]);
    }
}

// ---------------- kernel 4: global layernorm (in place on d_out) ----------------
__global__ void norm_kernel(float* __restrict__ out2, const float* __restrict__ accum,
                            const float* __restrict__ gn_w, const float* __restrict__ gn_b) {
    const int gid = blockIdx.x * 256 + threadIdx.x;
    const float invN = 1.f / 2097152.f;
    float mean = accum[0] * invN;
    float var = accum[1] * invN - mean * mean;
    float rstd = rsqrtf(var + 1e-5f);
    int base = gid * 4;
    int o = base >> 14;    // / HW
    float g = gn_w[o] * rstd;
    float b = gn_b[o];
    float4 v = *(const float4*)(out2 + base);
    float4 r;
    r.x = (v.x - mean) * g + b;
    r.y = (v.y - mean) * g + b;
    r.z = (v.z - mean) * g + b;
    r.w = (v.w - mean) * g + b;
    *(float4*)(out2 + base) = r;
}

extern "C" void kernel_launch(void* const* d_in, const int* in_sizes, int n_in,
                              void* d_out, int out_size, void* d_ws, size_t ws_size,
                              hipStream_t stream) {
    const float* query  = (const float*)d_in[0];
    const float* key    = (const float*)d_in[1];
    const float* value  = (const float*)d_in[2];
    const float* deform = (const float*)d_in[3];
    const float* w_q    = (const float*)d_in[4];
    const float* w_k    = (const float*)d_in[5];
    const float* w_v    = (const float*)d_in[6];
    const float* w_fc   = (const float*)d_in[7];
    const float* mlp_w1 = (const float*)d_in[8];
    const float* mlp_b1 = (const float*)d_in[9];
    const float* mlp_w2 = (const float*)d_in[10];
    const float* mlp_b2 = (const float*)d_in[11];
    const float* gn_w   = (const float*)d_in[12];
    const float* gn_b   = (const float*)d_in[13];

    float* out = (float*)d_out;
    float* ws  = (float*)d_ws;

    const size_t T = (size_t)HW * C;   // 2,097,152 floats = 8 MB
    float* q_t  = ws;
    float* k_t  = ws + T;
    float* v_t  = ws + 2 * T;
    float* ao_t = ws + 3 * T;
    float* acc  = ws + 4 * T;

    zero_acc_kernel<<<1, 1, 0, stream>>>(acc);
    qkv_kernel<<<1024, 256, 0, stream>>>(query, key, value, w_q, w_k, w_v, q_t, k_t, v_t);
    attn_kernel<<<16384, 128, 0, stream>>>(q_t, k_t, v_t, deform, ao_t);
    mlp_kernel<<<1024, 256, 0, stream>>>(ao_t, w_fc, mlp_w1, mlp_b1, mlp_w2, mlp_b2, out, acc);
    norm_kernel<<<2048, 256, 0, stream>>>(out, acc, gn_w, gn_b);
}